// Round 7
// baseline (228.265 us; speedup 1.0000x reference)
//
#include <hip/hip_runtime.h>
#include <hip/hip_bf16.h>

#define BB 16384   // batch
#define CC 4000    // agents (real)
#define CP 4096    // agents padded
#define DD 128     // feature dim
#define NT 16      // row-tiles per neg block (64 rows each)

typedef __attribute__((ext_vector_type(8))) short short8;
typedef __attribute__((ext_vector_type(4))) float f32x4;
typedef __attribute__((ext_vector_type(4))) unsigned int u32x4;

static __device__ __forceinline__ unsigned short f2bf(float f) {
  union { float f; unsigned int u; } v; v.f = f;
  unsigned int u = v.u;
  u += 0x7fffu + ((u >> 16) & 1u);   // RNE
  return (unsigned short)(u >> 16);
}

// ---- kernel 0: sim -> bitmask stream (pure copy-class kernel) ----
// H layout: uint32 H[rr][hs][64] ; rr = y*16384+row, hs = lane-half.
// word (hs, g*4+j) bit p  <->  col = g*256 + 4*(hs*32+p) + j
__global__ __launch_bounds__(256)
void mask_k(const float* __restrict__ sim_src,
            const float* __restrict__ sim_tgt,
            unsigned int* __restrict__ Hm) {
  const int li  = threadIdx.x & 63;
  const int wid = blockIdx.x * 4 + (threadIdx.x >> 6);   // 0..8191
  for (int rr = wid; rr < 2 * BB; rr += 8192) {
    const float* base = (rr < BB) ? sim_src + (size_t)rr * CC
                                  : sim_tgt + (size_t)(rr - BB) * CC;
    unsigned int* hrow = Hm + (size_t)rr * 128;
    #pragma unroll 4
    for (int g = 0; g < 16; ++g) {
      const int c0 = g * 256 + li * 4;
      float4 v = make_float4(0.f, 0.f, 0.f, 0.f);
      if (c0 + 3 < CC) v = *(const float4*)(base + c0);
      unsigned long long b0 = __ballot(v.x > 0.5f);
      unsigned long long b1 = __ballot(v.y > 0.5f);
      unsigned long long b2 = __ballot(v.z > 0.5f);
      unsigned long long b3 = __ballot(v.w > 0.5f);
      if (li < 8) {
        const int jj = li & 3, hs = li >> 2;
        unsigned long long bb = jj == 0 ? b0 : jj == 1 ? b1 : jj == 2 ? b2 : b3;
        hrow[hs * 64 + g * 4 + jj] = hs ? (unsigned int)(bb >> 32) : (unsigned int)bb;
      }
    }
  }
}

// ---- kernel 1: agents -> bf16 (padded to CP rows, zeros) + ||a||^2 ----
__global__ void prep_agents_k(const float* __restrict__ agents,
                              unsigned short* __restrict__ Ab,
                              float* __restrict__ an) {
  int t = threadIdx.x & 63;
  int c = blockIdx.x * 4 + (threadIdx.x >> 6);
  float n = 0.f;
  unsigned int pack = 0u;
  if (c < CC) {
    float2 f = *(const float2*)&agents[c * DD + t * 2];
    n = f.x * f.x + f.y * f.y;
    pack = ((unsigned int)f2bf(f.y) << 16) | (unsigned int)f2bf(f.x);
  }
  ((unsigned int*)Ab)[c * (DD / 2) + t] = pack;
  #pragma unroll
  for (int m = 1; m < 64; m <<= 1) n += __shfl_xor(n, m);
  if (t == 0) an[c] = n;
}

// ---- kernel 2: features -> bf16 + ||f||^2 ; loss_pos exact; sim at label;
//      zero the atomic accumulators ----
__global__ void prep_features_k(const float* __restrict__ fsrc,
                                const float* __restrict__ ftgt,
                                const float* __restrict__ agents,
                                const int* __restrict__ labels,
                                const float* __restrict__ sim_src,
                                unsigned short* __restrict__ Fsb,
                                unsigned short* __restrict__ Ftb,
                                float* __restrict__ fns,
                                float* __restrict__ fnt,
                                float* __restrict__ lp,
                                float* __restrict__ slab,
                                float* __restrict__ Sat,
                                float* __restrict__ Cat) {
  int t = threadIdx.x & 63;
  int b = blockIdx.x * 4 + (threadIdx.x >> 6);
  int y = blockIdx.y;
  const float* F = y ? ftgt : fsrc;
  unsigned short* Fb = y ? Ftb : Fsb;
  float2 f = *(const float2*)&F[b * DD + t * 2];
  float n = f.x * f.x + f.y * f.y;
  ((unsigned int*)Fb)[b * (DD / 2) + t] =
      ((unsigned int)f2bf(f.y) << 16) | (unsigned int)f2bf(f.x);
  float pl = 0.f;
  int lab = 0;
  if (y == 0) {
    lab = labels[b];
    float2 a = *(const float2*)&agents[lab * DD + t * 2];
    float dx = f.x - a.x, dy = f.y - a.y;
    pl = dx * dx + dy * dy;
  }
  #pragma unroll
  for (int m = 1; m < 64; m <<= 1) { n += __shfl_xor(n, m); pl += __shfl_xor(pl, m); }
  if (t == 0) {
    if (y) fnt[b] = n; else fns[b] = n;
    if (y == 0) {
      lp[b] = pl;
      slab[b] = sim_src[b * CC + lab];
    }
    Sat[y * BB + b] = 0.f;
    Cat[y * BB + b] = 0.f;
  }
}

// ---- kernel 3: masked hinge; agents register-resident; sim replaced by
//      bitmask dwordx4 loads (512 B/iter/wave). XCD-swizzled flat grid. ----
__global__ __launch_bounds__(256, 2)
void neg_kernel(const unsigned short* __restrict__ Fsb,
                const unsigned short* __restrict__ Ftb,
                const unsigned short* __restrict__ Ab,
                const float* __restrict__ an,
                const float* __restrict__ fns,
                const float* __restrict__ fnt,
                const unsigned int* __restrict__ Hm,
                float* __restrict__ Sat,
                float* __restrict__ Cat) {
  const int bid = blockIdx.x;          // 0..2047
  const int xcd = bid & 7;
  const int j   = bid >> 3;
  const int grp = xcd + 8 * (j >> 6);  // 0..31
  const int loc = j & 63;
  const int cb    = loc * 64;
  const int rbase = (grp & 15) * (64 * NT);
  const int y     = grp >> 4;

  const unsigned short* Fb = y ? Ftb : Fsb;
  const float* fn  = y ? fnt : fns;
  float* Sp = Sat + y * BB;
  float* Cp = Cat + y * BB;

  const int tid = threadIdx.x;
  const int w   = tid >> 6;
  const int l   = tid & 63;
  const int l15 = l & 15;
  const int lg  = l >> 4;

  __shared__ float Sbuf[64 * NT];
  __shared__ float Cbuf[64 * NT];

  // agents: A-frags + an, register-resident for the whole kernel
  short8 af[4][4];
  float4 av[4];
  #pragma unroll
  for (int nr = 0; nr < 4; nr++) {
    const short8* p = (const short8*)&Ab[(cb + nr * 16 + l15) * DD];
    #pragma unroll
    for (int ks = 0; ks < 4; ks++) af[nr][ks] = p[ks * 4 + lg];
    av[nr] = *(const float4*)&an[cb + nr * 16 + lg * 4];
  }

  // bitmask addressing for this lane
  const int hs = (cb >> 7) & 1;
  const int g  = cb >> 8;
  const int s0 = ((cb & 127) >> 2) + lg;        // bit pos of (nr=0, this lane)
  const unsigned int patt = 0x1111u << s0;      // bits for nr=0..3
  const unsigned int* mptr =
      Hm + (size_t)(y * BB + rbase + w * 16 + l15) * 128 + hs * 64 + g * 4;

  const unsigned short* fptr = &Fb[(size_t)(rbase + w * 16 + l15) * DD];
  const float* fnptr = &fn[rbase + w * 16 + l15];

  auto loadSet = [&](short8 (&ff)[4], float& fnc1, u32x4& mv) {
    const short8* p = (const short8*)fptr;
    #pragma unroll
    for (int ks = 0; ks < 4; ks++) ff[ks] = p[ks * 4 + lg];
    fnc1 = 1.f - *fnptr;
    mv = *(const u32x4*)mptr;
    fptr  += 64 * DD;
    fnptr += 64;
    mptr  += 64 * 128;
  };

  auto body = [&](const short8 (&ff)[4], float fnc1, u32x4 mv, int t) {
    float rowS = 0.f;
    int   cnt  = 0;
    #pragma unroll
    for (int nr = 0; nr < 4; nr++) {
      f32x4 acc = {0.f, 0.f, 0.f, 0.f};
      #pragma unroll
      for (int ks = 0; ks < 4; ks++)
        acc = __builtin_amdgcn_mfma_f32_16x16x32_bf16(af[nr][ks], ff[ks], acc, 0, 0, 0);
      const float* ap = (const float*)&av[nr];
      #pragma unroll
      for (int r = 0; r < 4; r++) {
        float c0 = fnc1 - ap[r];               // (1 - fn) - an
        float h  = fmaxf(0.f, fmaf(2.f, acc[r], c0));
        unsigned int bit = (mv[r] >> (s0 + 4 * nr)) & 1u;
        rowS += bit ? h : 0.f;
      }
    }
    #pragma unroll
    for (int r = 0; r < 4; r++) cnt += __popc(mv[r] & patt);
    float rowC = (float)cnt;
    rowS += __shfl_xor(rowS, 16); rowS += __shfl_xor(rowS, 32);
    rowC += __shfl_xor(rowC, 16); rowC += __shfl_xor(rowC, 32);
    if (lg == 0) {
      int idx = t * 64 + w * 16 + l15;
      Sbuf[idx] = rowS;
      Cbuf[idx] = rowC;
    }
  };

  short8 fA[4], fB[4];
  float nA, nB;
  u32x4 mA, mB;

  loadSet(fA, nA, mA);
  #pragma unroll 1
  for (int k = 0; k < 7; k++) {
    loadSet(fB, nB, mB);
    asm volatile("s_waitcnt vmcnt(6)" ::: "memory");
    body(fA, nA, mA, 2 * k);
    loadSet(fA, nA, mA);
    asm volatile("s_waitcnt vmcnt(6)" ::: "memory");
    body(fB, nB, mB, 2 * k + 1);
  }
  loadSet(fB, nB, mB);
  asm volatile("s_waitcnt vmcnt(6)" ::: "memory");
  body(fA, nA, mA, 14);
  asm volatile("s_waitcnt vmcnt(0)" ::: "memory");
  body(fB, nB, mB, 15);

  // bulk flush: one pass of atomics per block
  __syncthreads();
  #pragma unroll
  for (int i = 0; i < (64 * NT) / 256; i++) {
    int idx = i * 256 + tid;
    int row = rbase + idx;
    atomicAdd(&Sp[row], Sbuf[idx]);
    atomicAdd(&Cp[row], Cbuf[idx]);
  }
}

// ---- kernel 4: final reduction (label correction folded in) ----
__global__ void finalize_k(const float* __restrict__ lp,
                           const float* __restrict__ slab,
                           const float* __restrict__ Sat,
                           const float* __restrict__ Cat,
                           float* __restrict__ out) {
  const int t = threadIdx.x;  // 1024 threads, 1 block
  double ts = 0.0;
  long long nv = 0;
  for (int b = t; b < BB; b += 1024) {
    ts += (double)lp[b];
    float s = Sat[b], c = Cat[b];
    if (slab[b] > 0.5f) { s -= fmaxf(0.f, 1.f - lp[b]); c -= 1.f; }
    ts += (double)(s / fmaxf(c, 1.f));
    if (c > 0.f) nv++;
    s = Sat[BB + b]; c = Cat[BB + b];
    ts += (double)(s / fmaxf(c, 1.f));
    if (c > 0.f) nv++;
  }
  __shared__ double sd[1024];
  __shared__ long long sc[1024];
  sd[t] = ts; sc[t] = nv;
  __syncthreads();
  for (int s2 = 512; s2 > 0; s2 >>= 1) {
    if (t < s2) { sd[t] += sd[t + s2]; sc[t] += sc[t + s2]; }
    __syncthreads();
  }
  if (t == 0) {
    double nterms = (double)BB + (double)sc[0];
    out[0] = (float)(sd[0] / nterms);
  }
}

extern "C" void kernel_launch(void* const* d_in, const int* in_sizes, int n_in,
                              void* d_out, int out_size, void* d_ws, size_t ws_size,
                              hipStream_t stream) {
  const float* features = (const float*)d_in[0];
  const float* agents   = (const float*)d_in[1];
  const int*   labels   = (const int*)d_in[2];
  const float* sim_src  = (const float*)d_in[3];
  const float* ftgt     = (const float*)d_in[4];
  const float* sim_tgt  = (const float*)d_in[5];
  float* out = (float*)d_out;

  char* wsp = (char*)d_ws;
  unsigned short* Ab  = (unsigned short*)(wsp);                 // 1,048,576
  float*          an  = (float*)(wsp + 1048576);                // 16,384
  unsigned short* Fsb = (unsigned short*)(wsp + 1064960);       // 4,194,304
  unsigned short* Ftb = (unsigned short*)(wsp + 5259264);       // 4,194,304
  float*          fns = (float*)(wsp + 9453568);                // 65,536
  float*          fnt = (float*)(wsp + 9519104);                // 65,536
  float*          lp  = (float*)(wsp + 9584640);                // 65,536
  float*          slab= (float*)(wsp + 9650176);                // 65,536
  float*          Sat = (float*)(wsp + 9715712);                // 131,072
  float*          Cat = (float*)(wsp + 9846784);                // 131,072
  unsigned int*   Hm  = (unsigned int*)(wsp + 9977856);         // 16,777,216 (end 26,755,072)

  mask_k<<<dim3(2048), dim3(256), 0, stream>>>(sim_src, sim_tgt, Hm);
  prep_agents_k<<<dim3(CP / 4), dim3(256), 0, stream>>>(agents, Ab, an);
  prep_features_k<<<dim3(BB / 4, 2), dim3(256), 0, stream>>>(
      features, ftgt, agents, labels, sim_src, Fsb, Ftb, fns, fnt, lp, slab, Sat, Cat);
  neg_kernel<<<dim3(64 * 16 * 2), dim3(256), 0, stream>>>(
      Fsb, Ftb, Ab, an, fns, fnt, Hm, Sat, Cat);
  finalize_k<<<dim3(1), dim3(1024), 0, stream>>>(lp, slab, Sat, Cat, out);
}

// Round 8
// 156.238 us; speedup vs baseline: 1.4610x; 1.4610x over previous
//
#include <hip/hip_runtime.h>
#include <hip/hip_bf16.h>

#define BB 16384   // batch
#define CC 4000    // agents (real)
#define CP 4096    // agents padded
#define DD 128     // feature dim
#define NT 16      // row-tiles per neg block (64 rows each)

typedef __attribute__((ext_vector_type(8))) short short8;
typedef __attribute__((ext_vector_type(4))) float f32x4;

typedef const __attribute__((address_space(1))) void* gas_ptr;
typedef __attribute__((address_space(3))) void* las_ptr;

static __device__ __forceinline__ unsigned short f2bf(float f) {
  union { float f; unsigned int u; } v; v.f = f;
  unsigned int u = v.u;
  u += 0x7fffu + ((u >> 16) & 1u);   // RNE
  return (unsigned short)(u >> 16);
}

// ---- kernel 1: agents -> bf16 (padded to CP rows, zeros) + ||a||^2 ; zbuf ----
__global__ void prep_agents_k(const float* __restrict__ agents,
                              unsigned short* __restrict__ Ab,
                              float* __restrict__ an,
                              float* __restrict__ zbuf) {
  int t = threadIdx.x & 63;
  int c = blockIdx.x * 4 + (threadIdx.x >> 6);
  if (blockIdx.x == 0 && threadIdx.x < 64) zbuf[threadIdx.x] = 0.f;
  float n = 0.f;
  unsigned int pack = 0u;
  if (c < CC) {
    float2 f = *(const float2*)&agents[c * DD + t * 2];
    n = f.x * f.x + f.y * f.y;
    pack = ((unsigned int)f2bf(f.y) << 16) | (unsigned int)f2bf(f.x);
  }
  ((unsigned int*)Ab)[c * (DD / 2) + t] = pack;
  #pragma unroll
  for (int m = 1; m < 64; m <<= 1) n += __shfl_xor(n, m);
  if (t == 0) an[c] = n;
}

// ---- kernel 2: features -> bf16 + ||f||^2 ; loss_pos exact; sim at label;
//      zero the atomic accumulators ----
__global__ void prep_features_k(const float* __restrict__ fsrc,
                                const float* __restrict__ ftgt,
                                const float* __restrict__ agents,
                                const int* __restrict__ labels,
                                const float* __restrict__ sim_src,
                                unsigned short* __restrict__ Fsb,
                                unsigned short* __restrict__ Ftb,
                                float* __restrict__ fns,
                                float* __restrict__ fnt,
                                float* __restrict__ lp,
                                float* __restrict__ slab,
                                float* __restrict__ Sat,
                                float* __restrict__ Cat) {
  int t = threadIdx.x & 63;
  int b = blockIdx.x * 4 + (threadIdx.x >> 6);
  int y = blockIdx.y;
  const float* F = y ? ftgt : fsrc;
  unsigned short* Fb = y ? Ftb : Fsb;
  float2 f = *(const float2*)&F[b * DD + t * 2];
  float n = f.x * f.x + f.y * f.y;
  ((unsigned int*)Fb)[b * (DD / 2) + t] =
      ((unsigned int)f2bf(f.y) << 16) | (unsigned int)f2bf(f.x);
  float pl = 0.f;
  int lab = 0;
  if (y == 0) {
    lab = labels[b];
    float2 a = *(const float2*)&agents[lab * DD + t * 2];
    float dx = f.x - a.x, dy = f.y - a.y;
    pl = dx * dx + dy * dy;
  }
  #pragma unroll
  for (int m = 1; m < 64; m <<= 1) { n += __shfl_xor(n, m); pl += __shfl_xor(pl, m); }
  if (t == 0) {
    if (y) fnt[b] = n; else fns[b] = n;
    if (y == 0) {
      lp[b] = pl;
      slab[b] = sim_src[b * CC + lab];
    }
    Sat[y * BB + b] = 0.f;
    Cat[y * BB + b] = 0.f;
  }
}

// ---- kernel 3: masked hinge; agents register-resident, sim via global_load_lds
//      with NT (non-temporal) policy — bypass L3 allocation on the 524 MB
//      stream (R7 showed ~0% L3 hit + 3.3 TB/s throttle with allocating reads).
//      XCD-swizzled flat grid; 2-ahead pipeline; LDS-buffered atomics flush. ----
__global__ __launch_bounds__(256, 2)
void neg_kernel(const unsigned short* __restrict__ Fsb,
                const unsigned short* __restrict__ Ftb,
                const unsigned short* __restrict__ Ab,
                const float* __restrict__ an,
                const float* __restrict__ fns,
                const float* __restrict__ fnt,
                const float* __restrict__ sim_src,
                const float* __restrict__ sim_tgt,
                const float* __restrict__ zbuf,
                float* __restrict__ Sat,
                float* __restrict__ Cat) {
  // XCD swizzle: XCD(id)=id%8; each XCD owns 4 (row-slab, y) groups; the 64
  // col-blocks of a group share a 256 KB F slab -> F stays in that XCD's L2.
  const int bid = blockIdx.x;          // 0..2047
  const int xcd = bid & 7;
  const int j   = bid >> 3;            // 0..255
  const int grp = xcd + 8 * (j >> 6);  // 0..31
  const int loc = j & 63;              // col-block within group
  const int cb    = loc * 64;                 // agent col base
  const int rbase = (grp & 15) * (64 * NT);   // feature row base
  const int y     = grp >> 4;                 // src/tgt

  const unsigned short* Fb = y ? Ftb : Fsb;
  const float* fn  = y ? fnt : fns;
  const float* sim = y ? sim_tgt : sim_src;
  float* Sp = Sat + y * BB;
  float* Cp = Cat + y * BB;

  const int tid = threadIdx.x;
  const int w   = tid >> 6;
  const int l   = tid & 63;
  const int l15 = l & 15;
  const int lg  = l >> 4;

  __shared__ float simlds[3][4][1024];   // [buf][wave][16 rows x 64 cols]
  __shared__ float Sbuf[64 * NT];        // per-row hinge sums (this block's cols)
  __shared__ float Cbuf[64 * NT];        // per-row mask counts

  // agents: A-frags + an, register-resident for the whole kernel
  short8 af[4][4];
  float4 av[4];
  #pragma unroll
  for (int nr = 0; nr < 4; nr++) {
    const short8* p = (const short8*)&Ab[(cb + nr * 16 + l15) * DD];
    #pragma unroll
    for (int ks = 0; ks < 4; ks++) af[nr][ks] = p[ks * 4 + lg];
    av[nr] = *(const float4*)&an[cb + nr * 16 + lg * 4];
  }

  // sim staging source pointers (per lane, 4 gll instrs jj=0..3)
  // LDS linear dest byte = jj*1024 + lane*16 -> (row = jj*4+lg, slot = l15);
  // content = sim[row][cb + (slot ^ (row&7))*4 .. +3]  (XOR pre-swizzle)
  const char* sp_[4];
  long step_[4];
  #pragma unroll
  for (int jj = 0; jj < 4; jj++) {
    int row  = jj * 4 + lg;
    int c16  = l15 ^ (row & 7);
    bool valid = (cb + c16 * 4) < CC;
    sp_[jj] = valid
        ? (const char*)&sim[(size_t)(rbase + w * 16 + row) * CC + cb + c16 * 4]
        : (const char*)zbuf;
    step_[jj] = valid ? (long)(64 * (size_t)CC * 4) : 0;
  }

  const unsigned short* fptr = &Fb[(size_t)(rbase + w * 16 + l15) * DD];
  const float* fnptr = &fn[rbase + w * 16 + l15];

  auto stage = [&](int buf) {
    #pragma unroll
    for (int jj = 0; jj < 4; jj++) {
      // aux=2 -> NT cache policy (SLC bit => 'nt' on gfx950): stream, no L3 alloc
      __builtin_amdgcn_global_load_lds((gas_ptr)(const void*)sp_[jj],
                                       (las_ptr)(void*)&simlds[buf][w][jj * 256],
                                       16, 0, 2);
      sp_[jj] += step_[jj];
    }
  };

  auto loadF = [&](short8 (&ff)[4], float& fnc1) {
    const short8* p = (const short8*)fptr;
    #pragma unroll
    for (int ks = 0; ks < 4; ks++) ff[ks] = p[ks * 4 + lg];
    fnc1 = 1.f - *fnptr;
    fptr  += 64 * DD;
    fnptr += 64;
  };

  auto body = [&](int buf, const short8 (&ff)[4], float fnc1, int t) {
    float4 sv[4];
    #pragma unroll
    for (int nr = 0; nr < 4; nr++) {
      int slot = (nr * 4 + lg) ^ (l15 & 7);
      sv[nr] = *(const float4*)&simlds[buf][w][l15 * 64 + slot * 4];
    }
    float rowS = 0.f, rowC = 0.f;
    #pragma unroll
    for (int nr = 0; nr < 4; nr++) {
      f32x4 acc = {0.f, 0.f, 0.f, 0.f};
      #pragma unroll
      for (int ks = 0; ks < 4; ks++)
        acc = __builtin_amdgcn_mfma_f32_16x16x32_bf16(af[nr][ks], ff[ks], acc, 0, 0, 0);
      const float* ap = (const float*)&av[nr];
      const float* sp = (const float*)&sv[nr];
      #pragma unroll
      for (int r = 0; r < 4; r++) {
        float c0 = fnc1 - ap[r];               // (1 - fn) - an
        float t2 = fmaf(2.f, acc[r], c0);      // 1 - dist
        float h  = fmaxf(0.f, t2);
        bool  m  = sp[r] > 0.5f;
        rowS += m ? h : 0.f;
        rowC += m ? 1.f : 0.f;
      }
    }
    rowS += __shfl_xor(rowS, 16); rowS += __shfl_xor(rowS, 32);
    rowC += __shfl_xor(rowC, 16); rowC += __shfl_xor(rowC, 32);
    if (lg == 0) {
      int idx = t * 64 + w * 16 + l15;
      Sbuf[idx] = rowS;
      Cbuf[idx] = rowC;
    }
  };

  short8 fA[4], fB[4], fC[4];
  float nA, nB, nC;

  // prologue: tiles 0,1 in flight (18 ops)
  stage(0); loadF(fA, nA);
  stage(1); loadF(fB, nB);

  // steady state: 2-ahead, 9 ops per phase, wait to 18 (= 2 newer phases)
  #pragma unroll 1
  for (int k = 0; k < 4; k++) {
    stage(2); loadF(fC, nC);                          // tile 3k+2
    asm volatile("s_waitcnt vmcnt(18)" ::: "memory"); // tile 3k ready
    body(0, fA, nA, 3 * k);
    stage(0); loadF(fA, nA);                          // tile 3k+3
    asm volatile("s_waitcnt vmcnt(18)" ::: "memory"); // tile 3k+1 ready
    body(1, fB, nB, 3 * k + 1);
    stage(1); loadF(fB, nB);                          // tile 3k+4
    asm volatile("s_waitcnt vmcnt(18)" ::: "memory"); // tile 3k+2 ready
    body(2, fC, nC, 3 * k + 2);
  }
  // epilogue: tiles 12..15 (stages for 14,15, then drain)
  stage(2); loadF(fC, nC);                            // tile 14
  asm volatile("s_waitcnt vmcnt(18)" ::: "memory");
  body(0, fA, nA, 12);
  stage(0); loadF(fA, nA);                            // tile 15
  asm volatile("s_waitcnt vmcnt(18)" ::: "memory");
  body(1, fB, nB, 13);
  asm volatile("s_waitcnt vmcnt(9)" ::: "memory");
  body(2, fC, nC, 14);
  asm volatile("s_waitcnt vmcnt(0)" ::: "memory");
  body(0, fA, nA, 15);

  // bulk flush: one pass of atomics per block, off the loop's critical path
  __syncthreads();
  #pragma unroll
  for (int i = 0; i < (64 * NT) / 256; i++) {
    int idx = i * 256 + tid;
    int row = rbase + idx;
    atomicAdd(&Sp[row], Sbuf[idx]);
    atomicAdd(&Cp[row], Cbuf[idx]);
  }
}

// ---- kernel 4: final reduction (label correction folded in) ----
__global__ void finalize_k(const float* __restrict__ lp,
                           const float* __restrict__ slab,
                           const float* __restrict__ Sat,
                           const float* __restrict__ Cat,
                           float* __restrict__ out) {
  const int t = threadIdx.x;  // 1024 threads, 1 block
  double ts = 0.0;
  long long nv = 0;
  for (int b = t; b < BB; b += 1024) {
    ts += (double)lp[b];
    float s = Sat[b], c = Cat[b];
    if (slab[b] > 0.5f) { s -= fmaxf(0.f, 1.f - lp[b]); c -= 1.f; }
    ts += (double)(s / fmaxf(c, 1.f));
    if (c > 0.f) nv++;
    s = Sat[BB + b]; c = Cat[BB + b];
    ts += (double)(s / fmaxf(c, 1.f));
    if (c > 0.f) nv++;
  }
  __shared__ double sd[1024];
  __shared__ long long sc[1024];
  sd[t] = ts; sc[t] = nv;
  __syncthreads();
  for (int s2 = 512; s2 > 0; s2 >>= 1) {
    if (t < s2) { sd[t] += sd[t + s2]; sc[t] += sc[t + s2]; }
    __syncthreads();
  }
  if (t == 0) {
    double nterms = (double)BB + (double)sc[0];
    out[0] = (float)(sd[0] / nterms);
  }
}

extern "C" void kernel_launch(void* const* d_in, const int* in_sizes, int n_in,
                              void* d_out, int out_size, void* d_ws, size_t ws_size,
                              hipStream_t stream) {
  const float* features = (const float*)d_in[0];
  const float* agents   = (const float*)d_in[1];
  const int*   labels   = (const int*)d_in[2];
  const float* sim_src  = (const float*)d_in[3];
  const float* ftgt     = (const float*)d_in[4];
  const float* sim_tgt  = (const float*)d_in[5];
  float* out = (float*)d_out;

  char* wsp = (char*)d_ws;
  unsigned short* Ab  = (unsigned short*)(wsp);                 // 1,048,576
  float*          an  = (float*)(wsp + 1048576);                // 16,384
  unsigned short* Fsb = (unsigned short*)(wsp + 1064960);       // 4,194,304
  unsigned short* Ftb = (unsigned short*)(wsp + 5259264);       // 4,194,304
  float*          fns = (float*)(wsp + 9453568);                // 65,536
  float*          fnt = (float*)(wsp + 9519104);                // 65,536
  float*          lp  = (float*)(wsp + 9584640);                // 65,536
  float*          slab= (float*)(wsp + 9650176);                // 65,536
  float*          Sat = (float*)(wsp + 9715712);                // 131,072
  float*          Cat = (float*)(wsp + 9846784);                // 131,072
  float*          zbuf= (float*)(wsp + 9977856);                // 256     (end 9,978,112)

  prep_agents_k<<<dim3(CP / 4), dim3(256), 0, stream>>>(agents, Ab, an, zbuf);
  prep_features_k<<<dim3(BB / 4, 2), dim3(256), 0, stream>>>(
      features, ftgt, agents, labels, sim_src, Fsb, Ftb, fns, fnt, lp, slab, Sat, Cat);
  neg_kernel<<<dim3(64 * 16 * 2), dim3(256), 0, stream>>>(
      Fsb, Ftb, Ab, an, fns, fnt, sim_src, sim_tgt, zbuf, Sat, Cat);
  finalize_k<<<dim3(1), dim3(1024), 0, stream>>>(lp, slab, Sat, Cat, out);
}